// Round 10
// baseline (2218.595 us; speedup 1.0000x reference)
//
#include <hip/hip_runtime.h>

// Sizes (fixed for this problem)
#define T_TOK 1024
#define H_DIM 2048
#define E_NUM 32
#define I_DIM 1024
#define IS_DIM 2048

typedef float  f32x4 __attribute__((ext_vector_type(4)));
typedef short  s16x8 __attribute__((ext_vector_type(8)));
typedef unsigned short u16x4 __attribute__((ext_vector_type(4)));
typedef unsigned short u16x8 __attribute__((ext_vector_type(8)));

__device__ __forceinline__ unsigned short f2bf(float f) {
    unsigned u = __builtin_bit_cast(unsigned, f);
    u = (u + 0x7fffu + ((u >> 16) & 1u)) >> 16;
    return (unsigned short)u;
}
__device__ __forceinline__ float bf2f(unsigned short h) {
    return __builtin_bit_cast(float, (unsigned)h << 16);
}

// LDS column swizzle: rows are 32 u16 (64 B); XOR col-block (8 u16) with
// row bits so strided row access spreads across banks; 16B alignment kept.
__device__ __forceinline__ int swz(int r, int c) {
    return (r << 5) + (c ^ (((r >> 2) & 3) << 3));
}

// ---------------------------------------------------------------------------
// x (fp32) -> bf16 once; all GEMM A-operands are bf16.
// ---------------------------------------------------------------------------
__global__ __launch_bounds__(256) void cvt_k(
    const float* __restrict__ x, unsigned short* __restrict__ xb)
{
    const int i = (blockIdx.x * 256 + threadIdx.x) * 8;
    f32x4 a = *(const f32x4*)(x + i);
    f32x4 b = *(const f32x4*)(x + i + 4);
    u16x8 h = { f2bf(a[0]), f2bf(a[1]), f2bf(a[2]), f2bf(a[3]),
                f2bf(b[0]), f2bf(b[1]), f2bf(b[2]), f2bf(b[3]) };
    *(u16x8*)(xb + i) = h;
}

// ---------------------------------------------------------------------------
// silu(g)*u elementwise, bf16 in / bf16 out (out may alias g).
// ---------------------------------------------------------------------------
__global__ __launch_bounds__(256) void silu_k(
    const unsigned short* __restrict__ g, const unsigned short* __restrict__ u,
    unsigned short* __restrict__ o)
{
    const int i = (blockIdx.x * 256 + threadIdx.x) * 8;
    u16x8 gv = *(const u16x8*)(g + i);
    u16x8 uv = *(const u16x8*)(u + i);
    u16x8 r;
    #pragma unroll
    for (int j = 0; j < 8; ++j) {
        float gf = bf2f(gv[j]);
        float uf = bf2f(uv[j]);
        r[j] = f2bf(gf / (1.f + expf(-gf)) * uf);
    }
    *(u16x8*)(o + i) = r;
}

// ---------------------------------------------------------------------------
// Routing: 4 tokens per 256-thread block, one wave per token.
// ---------------------------------------------------------------------------
__global__ __launch_bounds__(256) void route_k(
    const float* __restrict__ x, const float* __restrict__ gw,
    const float* __restrict__ bias, int* __restrict__ tidx,
    float* __restrict__ tw)
{
    const int w = threadIdx.x >> 6;
    const int lane = threadIdx.x & 63;
    const int t = blockIdx.x * 4 + w;
    __shared__ float xs[4][H_DIM];
    __shared__ float sfc[4][E_NUM];
    __shared__ float sc[4][E_NUM];

    for (int i = threadIdx.x; i < 4 * (H_DIM / 4); i += 256) {
        int tt = i >> 9;
        int c = i & 511;
        *(f32x4*)&xs[tt][c * 4] =
            *(const f32x4*)(x + (size_t)(blockIdx.x * 4 + tt) * H_DIM + c * 4);
    }
    __syncthreads();

    const int eq = (lane & 7) * 4;
    const int hs = lane >> 3;
    f32x4 acc = {0.f, 0.f, 0.f, 0.f};
    #pragma unroll 4
    for (int h = hs; h < H_DIM; h += 8) {
        float xv = xs[w][h];
        f32x4 gv = *(const f32x4*)(gw + (size_t)h * E_NUM + eq);
        acc += gv * xv;
    }
    #pragma unroll
    for (int m = 8; m < 64; m <<= 1) {
        acc[0] += __shfl_xor(acc[0], m);
        acc[1] += __shfl_xor(acc[1], m);
        acc[2] += __shfl_xor(acc[2], m);
        acc[3] += __shfl_xor(acc[3], m);
    }
    if (lane < 8) {
        #pragma unroll
        for (int j = 0; j < 4; ++j) {
            float s = 1.f / (1.f + expf(-acc[j]));
            sc[w][eq + j] = s;
            sfc[w][eq + j] = s + bias[eq + j];
        }
    }
    __syncthreads();

    if (lane == 0) {
        float gs[4];
        for (int gg = 0; gg < 4; ++gg) {
            float m1 = -1e30f, m2 = -1e30f;
            for (int j = 0; j < 8; ++j) {
                float v = sfc[w][gg * 8 + j];
                if (v > m1) { m2 = m1; m1 = v; }
                else if (v > m2) { m2 = v; }
            }
            gs[gg] = m1 + m2;
        }
        int g1 = 0;
        for (int gg = 1; gg < 4; ++gg) if (gs[gg] > gs[g1]) g1 = gg;
        int g2 = (g1 == 0) ? 1 : 0;
        for (int gg = 0; gg < 4; ++gg)
            if (gg != g1 && gs[gg] > gs[g2]) g2 = gg;

        unsigned allow = (0xFFu << (g1 * 8)) | (0xFFu << (g2 * 8));
        unsigned taken = 0u;
        int   isel[8];
        float wsel[8];
        float wsum = 0.f;
        for (int k = 0; k < 8; ++k) {
            int best = 0; float bv = -1e30f;
            for (int e2 = 0; e2 < 32; ++e2) {
                if (((allow >> e2) & 1u) && !((taken >> e2) & 1u)) {
                    float v = sfc[w][e2];
                    if (v > bv) { bv = v; best = e2; }
                }
            }
            taken |= 1u << best;
            isel[k] = best;
            wsel[k] = sc[w][best];
            wsum += sc[w][best];
        }
        const float f = 2.5f / wsum;
        for (int k = 0; k < 8; ++k) {
            tidx[t * 8 + k] = isel[k];
            tw[t * 8 + k] = wsel[k] * f;
        }
    }
}

// ---------------------------------------------------------------------------
// Build per-expert token lists (ascending token id). One wave per expert.
// ---------------------------------------------------------------------------
__global__ __launch_bounds__(64) void build_k(
    const int* __restrict__ tidx, const float* __restrict__ tw,
    int* __restrict__ ltok, float* __restrict__ lw, int* __restrict__ counts)
{
    const int e = blockIdx.x;
    const int lane = threadIdx.x;
    int cnt = 0;
    for (int t0 = 0; t0 < T_TOK; t0 += 64) {
        const int t = t0 + lane;
        int sel = 0; float w = 0.f;
        #pragma unroll
        for (int k = 0; k < 8; ++k) {
            if (tidx[t * 8 + k] == e) { sel = 1; w = tw[t * 8 + k]; }
        }
        unsigned long long m = __ballot(sel);
        int pos = __popcll(m & ((1ull << lane) - 1ull));
        if (sel) {
            ltok[e * T_TOK + cnt + pos] = t;
            lw[e * T_TOK + cnt + pos] = w;
        }
        cnt += __popcll(m);
    }
    if (lane == 0) counts[e] = cnt;
}

__global__ void prefix_k(const int* __restrict__ counts, int* __restrict__ offsets)
{
    if (threadIdx.x == 0) {
        int off = 0;
        for (int e = 0; e < E_NUM; ++e) { offsets[e] = off; off += counts[e]; }
    }
}

// ---------------------------------------------------------------------------
// GEMM: 128x32 tile, BK=32, 256 threads (4 waves, one 32-row strip each),
// double-buffered swizzled LDS, depth-2 X/Y register pipeline (R8 schedule).
// Single B matrix per block (low VGPR/LDS -> 6-8 blocks/CU).
// MSPLIT: y-grid doubled; second half uses (B2, out2)   [gate|up un-fused]
// EXPERT: blockIdx.z = expert;   GATHER: A rows via ltok
// OUTMODE: 0 = bf16 store, 1 = f32 store, 2 = f32 scaled atomicAdd
// KSPLIT: blockIdx.x = K-chunk (partials combine via atomic OUTMODE=2)
// ---------------------------------------------------------------------------
template<int MSPLIT, int EXPERT, int GATHER, int OUTMODE, int KSPLIT>
__global__ __launch_bounds__(256, 6) void gemm_k(
    const unsigned short* __restrict__ A,
    const float* __restrict__ B1g, const float* __restrict__ B2g,
    void* __restrict__ out1v, void* __restrict__ out2v,
    const int* __restrict__ counts, const int* __restrict__ offsets,
    const int* __restrict__ ltok, const float* __restrict__ lw,
    int M, int N, int K)
{
    constexpr int BM = 128;
    constexpr int WR = 32;             // rows per wave strip
    constexpr int FM = 2;              // 16-row frags per wave
    constexpr int NB = 2;              // u16x8 A chunks per thread (KSP=16)

    const int e = blockIdx.z;
    const int Mloc = EXPERT ? counts[e] : M;
    const int rb = EXPERT ? offsets[e] : 0;

    int ymat = 0, ypanel = blockIdx.y;
    if (MSPLIT) {
        const int half = gridDim.y >> 1;
        ymat = (blockIdx.y >= half) ? 1 : 0;
        ypanel = blockIdx.y - ymat * half;
    }
    const int col0 = ypanel * 32;
    const float* B = ymat ? B2g : B1g;
    void* outv = ymat ? out2v : out1v;
    if (EXPERT) B += (size_t)e * K * N;

    const int kbase = (KSPLIT > 1) ? blockIdx.x * (K / KSPLIT) : 0;
    const int nk = (K / KSPLIT) >> 5;                  // even
    const int m0 = (KSPLIT > 1) ? 0 : blockIdx.x * BM;
    const int mstep = ((KSPLIT > 1) ? 1 : gridDim.x) * BM;

    __shared__ unsigned short lA[2][BM * 32];
    __shared__ unsigned short lB[2][32 * 32];

    const int tid = threadIdx.x;
    const int lane = tid & 63;
    const int wv = tid >> 6;           // 0..3 = M strip

    const int arow = tid >> 1;         // 0..127
    const int akb  = (tid & 1) * 16;   // k half

    // ---- B staging: 64 threads, 4k x 4n micro-tile each ----
    const bool doB = tid < 64;
    const int nq = tid & 7;            // n-quad 0..7
    const int kq = (tid >> 3) & 7;     // k-quad 0..7
    const float* bp = B + (size_t)(kbase + 4 * kq) * N + col0 + nq * 4;

    f32x4 acc1[FM][2];
    u16x8 pbaX[NB], pbaY[NB];
    f32x4 pbX[4], pbY[4];
    const unsigned short* apb = nullptr;

    auto loadT = [&](int k0, u16x8 (&pba)[NB], f32x4 (&pb)[4]) {
        #pragma unroll
        for (int i = 0; i < NB; ++i)
            pba[i] = *(const u16x8*)(apb + k0 + i * 8);
        if (doB) {
            #pragma unroll
            for (int j = 0; j < 4; ++j)
                pb[j] = *(const f32x4*)(bp + (size_t)(k0 + j) * N);
        }
    };

    auto storeT = [&](int p, u16x8 (&pba)[NB], f32x4 (&pb)[4]) {
        #pragma unroll
        for (int i = 0; i < NB; ++i)
            *(u16x8*)&lA[p][swz(arow, akb + i * 8)] = pba[i];
        if (doB) {
            #pragma unroll
            for (int j2 = 0; j2 < 4; ++j2) {
                u16x4 h = { f2bf(pb[0][j2]), f2bf(pb[1][j2]),
                            f2bf(pb[2][j2]), f2bf(pb[3][j2]) };
                *(u16x4*)&lB[p][swz(nq * 4 + j2, kq * 4)] = h;
            }
        }
    };

    auto compute = [&](int p) {
        const int koff = (lane >> 4) * 8;
        s16x8 af[FM], bf[2];
        #pragma unroll
        for (int fm = 0; fm < FM; ++fm)
            af[fm] = *(const s16x8*)&lA[p][swz(wv * WR + fm * 16 + (lane & 15), koff)];
        #pragma unroll
        for (int fn = 0; fn < 2; ++fn)
            bf[fn] = *(const s16x8*)&lB[p][swz(fn * 16 + (lane & 15), koff)];
        #pragma unroll
        for (int fm = 0; fm < FM; ++fm)
            #pragma unroll
            for (int fn = 0; fn < 2; ++fn)
                acc1[fm][fn] = __builtin_amdgcn_mfma_f32_16x16x32_bf16(
                    af[fm], bf[fn], acc1[fm][fn], 0, 0, 0);
    };

    for (int row0 = m0; row0 < Mloc; row0 += mstep) {
        {
            int rr = row0 + arow;
            if (rr >= Mloc) rr = Mloc - 1;
            int grow = GATHER ? ltok[e * T_TOK + rr] : (rb + rr);
            apb = A + (size_t)grow * K + kbase + akb;
        }
        #pragma unroll
        for (int a = 0; a < FM; ++a)
            #pragma unroll
            for (int b = 0; b < 2; ++b)
                acc1[a][b] = f32x4{0.f, 0.f, 0.f, 0.f};

        loadT(0, pbaX, pbX);
        loadT(32, pbaY, pbY);
        __syncthreads();               // prior m-tile done with LDS
        storeT(0, pbaX, pbX);
        __syncthreads();

        for (int kt = 0; kt < nk; kt += 2) {
            if (kt + 2 < nk) loadT((kt + 2) << 5, pbaX, pbX);
            compute(0);
            storeT(1, pbaY, pbY);
            __syncthreads();
            if (kt + 3 < nk) loadT((kt + 3) << 5, pbaY, pbY);
            compute(1);
            if (kt + 2 < nk) {
                storeT(0, pbaX, pbX);
                __syncthreads();
            }
        }

        // ---- epilogue ----
        const int fr = (lane >> 4) << 2;
        const int fc = lane & 15;
        if (OUTMODE == 0) {
            unsigned short* outp = (unsigned short*)outv;
            #pragma unroll
            for (int fm = 0; fm < FM; ++fm)
                #pragma unroll
                for (int fn = 0; fn < 2; ++fn)
                    #pragma unroll
                    for (int j = 0; j < 4; ++j) {
                        int r = wv * WR + fm * 16 + fr + j;
                        if (row0 + r < Mloc) {
                            int cc = col0 + fn * 16 + fc;
                            outp[(size_t)(rb + row0 + r) * N + cc] = f2bf(acc1[fm][fn][j]);
                        }
                    }
        } else if (OUTMODE == 1) {
            float* outp = (float*)outv;
            #pragma unroll
            for (int fm = 0; fm < FM; ++fm)
                #pragma unroll
                for (int fn = 0; fn < 2; ++fn)
                    #pragma unroll
                    for (int j = 0; j < 4; ++j) {
                        int r = wv * WR + fm * 16 + fr + j;
                        if (row0 + r < Mloc) {
                            int cc = col0 + fn * 16 + fc;
                            outp[(size_t)(row0 + r) * N + cc] = acc1[fm][fn][j];
                        }
                    }
        } else {
            float* outp = (float*)outv;
            #pragma unroll
            for (int fm = 0; fm < FM; ++fm)
                #pragma unroll
                for (int fn = 0; fn < 2; ++fn)
                    #pragma unroll
                    for (int j = 0; j < 4; ++j) {
                        int r = wv * WR + fm * 16 + fr + j;
                        if (row0 + r < Mloc) {
                            int tok = ltok[e * T_TOK + row0 + r];
                            float wr = lw[e * T_TOK + row0 + r];
                            int cc = col0 + fn * 16 + fc;
                            atomicAdd(outp + (size_t)tok * N + cc, acc1[fm][fn][j] * wr);
                        }
                    }
        }
    }
}

// ---------------------------------------------------------------------------
extern "C" void kernel_launch(void* const* d_in, const int* in_sizes, int n_in,
                              void* d_out, int out_size, void* d_ws, size_t ws_size,
                              hipStream_t stream) {
    const float* x       = (const float*)d_in[0];
    const float* gate_w  = (const float*)d_in[1];
    const float* bias    = (const float*)d_in[2];
    const float* w_gate  = (const float*)d_in[3];
    const float* w_up    = (const float*)d_in[4];
    const float* w_down  = (const float*)d_in[5];
    const float* sw_gate = (const float*)d_in[6];
    const float* sw_up   = (const float*)d_in[7];
    const float* sw_down = (const float*)d_in[8];
    float* out = (float*)d_out;

    char* ws = (char*)d_ws;
    int*   topk_idx = (int*)ws;                                   // 32 KB
    float* topk_w   = (float*)(ws + 32768);                       // 32 KB
    int*   counts   = (int*)(ws + 65536);                         // 128 B
    int*   offsets  = (int*)(ws + 65536 + 128);                   // 128 B
    int*   ltok     = (int*)(ws + 65536 + 256);                   // 128 KB
    float* lw       = (float*)(ws + 65536 + 256 + 131072);        // 128 KB
    unsigned short* xbf = (unsigned short*)(ws + 65536 + 256 + 262144);  // 4 MB
    unsigned short* g_s = xbf + (size_t)T_TOK * H_DIM;                   // 4 MB
    unsigned short* u_s = g_s + (size_t)T_TOK * IS_DIM;                  // 4 MB
    unsigned short* g_r = u_s + (size_t)T_TOK * IS_DIM;                  // 16 MB
    unsigned short* u_r = g_r + (size_t)T_TOK * 8 * I_DIM;               // 16 MB

    cvt_k<<<T_TOK * H_DIM / 2048, 256, 0, stream>>>(x, xbf);
    route_k<<<T_TOK / 4, 256, 0, stream>>>(x, gate_w, bias, topk_idx, topk_w);
    build_k<<<E_NUM, 64, 0, stream>>>(topk_idx, topk_w, ltok, lw, counts);
    prefix_k<<<1, 64, 0, stream>>>(counts, offsets);

    // shared gate/up (matrix-split): y 0..63 -> gate, 64..127 -> up
    gemm_k<1,0,0,0,1><<<dim3(8, 128, 1), 256, 0, stream>>>(
        xbf, sw_gate, sw_up, g_s, u_s, nullptr, nullptr, nullptr, nullptr,
        T_TOK, IS_DIM, H_DIM);
    silu_k<<<T_TOK * IS_DIM / 2048, 256, 0, stream>>>(g_s, u_s, g_s);

    // routed gate/up (matrix-split): 2048 blocks, weight panels read once
    gemm_k<1,1,1,0,1><<<dim3(1, 64, E_NUM), 256, 0, stream>>>(
        xbf, w_gate, w_up, g_r, u_r, counts, offsets, ltok, lw,
        T_TOK, I_DIM, H_DIM);
    silu_k<<<T_TOK * 8 * I_DIM / 2048, 256, 0, stream>>>(g_r, u_r, g_r);

    // shared down -> out (f32 store, initializes out)
    gemm_k<0,0,0,1,1><<<dim3(8, 64, 1), 256, 0, stream>>>(
        g_s, sw_down, nullptr, out, nullptr, nullptr, nullptr, nullptr, nullptr,
        T_TOK, H_DIM, IS_DIM);

    // routed down -> out (scaled atomicAdd), K split in 2: 4096 blocks
    gemm_k<0,1,0,2,2><<<dim3(2, 64, E_NUM), 256, 0, stream>>>(
        g_r, w_down, nullptr, out, nullptr, counts, offsets, ltok, lw,
        T_TOK, H_DIM, I_DIM);
}

// Round 11
// 850.124 us; speedup vs baseline: 2.6097x; 2.6097x over previous
//
#include <hip/hip_runtime.h>

// Sizes (fixed for this problem)
#define T_TOK 1024
#define H_DIM 2048
#define E_NUM 32
#define I_DIM 1024
#define IS_DIM 2048

typedef float  f32x4 __attribute__((ext_vector_type(4)));
typedef short  s16x8 __attribute__((ext_vector_type(8)));
typedef unsigned short u16x4 __attribute__((ext_vector_type(4)));
typedef unsigned short u16x8 __attribute__((ext_vector_type(8)));

__device__ __forceinline__ unsigned short f2bf(float f) {
    unsigned u = __builtin_bit_cast(unsigned, f);
    u = (u + 0x7fffu + ((u >> 16) & 1u)) >> 16;
    return (unsigned short)u;
}
__device__ __forceinline__ float bf2f(unsigned short h) {
    return __builtin_bit_cast(float, (unsigned)h << 16);
}

// Swizzled element index into a [64][128] bf16 LDS tile (rows = n, cols = k).
// 16B chunks XORed with a row hash -> conflict-free ds_read_b128 columns-of-n
// reads AND spread ds_write_b64 staging writes.
__device__ __forceinline__ int swzB(int n, int ke) {
    int chunk = (ke >> 3) ^ ((n ^ (n >> 2)) & 15);
    return n * 128 + (chunk << 3) + (ke & 7);
}

// ---------------------------------------------------------------------------
// x (fp32) -> bf16 once; all GEMM A-operands are bf16.
// ---------------------------------------------------------------------------
__global__ __launch_bounds__(256) void cvt_k(
    const float* __restrict__ x, unsigned short* __restrict__ xb)
{
    const int i = (blockIdx.x * 256 + threadIdx.x) * 8;
    f32x4 a = *(const f32x4*)(x + i);
    f32x4 b = *(const f32x4*)(x + i + 4);
    u16x8 h = { f2bf(a[0]), f2bf(a[1]), f2bf(a[2]), f2bf(a[3]),
                f2bf(b[0]), f2bf(b[1]), f2bf(b[2]), f2bf(b[3]) };
    *(u16x8*)(xb + i) = h;
}

// ---------------------------------------------------------------------------
// silu(g)*u elementwise, bf16 in / bf16 out (out aliases g).
// ---------------------------------------------------------------------------
__global__ __launch_bounds__(256) void silu_k(
    const unsigned short* __restrict__ g, const unsigned short* __restrict__ u,
    unsigned short* __restrict__ o)
{
    const int i = (blockIdx.x * 256 + threadIdx.x) * 8;
    u16x8 gv = *(const u16x8*)(g + i);
    u16x8 uv = *(const u16x8*)(u + i);
    u16x8 r;
    #pragma unroll
    for (int j = 0; j < 8; ++j) {
        float gf = bf2f(gv[j]);
        float uf = bf2f(uv[j]);
        r[j] = f2bf(gf / (1.f + expf(-gf)) * uf);
    }
    *(u16x8*)(o + i) = r;
}

// ---------------------------------------------------------------------------
// Routing: 4 tokens per 256-thread block, one wave per token.
// ---------------------------------------------------------------------------
__global__ __launch_bounds__(256) void route_k(
    const float* __restrict__ x, const float* __restrict__ gw,
    const float* __restrict__ bias, int* __restrict__ tidx,
    float* __restrict__ tw)
{
    const int w = threadIdx.x >> 6;
    const int lane = threadIdx.x & 63;
    const int t = blockIdx.x * 4 + w;
    __shared__ float xs[4][H_DIM];
    __shared__ float sfc[4][E_NUM];
    __shared__ float sc[4][E_NUM];

    for (int i = threadIdx.x; i < 4 * (H_DIM / 4); i += 256) {
        int tt = i >> 9;
        int c = i & 511;
        *(f32x4*)&xs[tt][c * 4] =
            *(const f32x4*)(x + (size_t)(blockIdx.x * 4 + tt) * H_DIM + c * 4);
    }
    __syncthreads();

    const int eq = (lane & 7) * 4;
    const int hs = lane >> 3;
    f32x4 acc = {0.f, 0.f, 0.f, 0.f};
    #pragma unroll 4
    for (int h = hs; h < H_DIM; h += 8) {
        float xv = xs[w][h];
        f32x4 gv = *(const f32x4*)(gw + (size_t)h * E_NUM + eq);
        acc += gv * xv;
    }
    #pragma unroll
    for (int m = 8; m < 64; m <<= 1) {
        acc[0] += __shfl_xor(acc[0], m);
        acc[1] += __shfl_xor(acc[1], m);
        acc[2] += __shfl_xor(acc[2], m);
        acc[3] += __shfl_xor(acc[3], m);
    }
    if (lane < 8) {
        #pragma unroll
        for (int j = 0; j < 4; ++j) {
            float s = 1.f / (1.f + expf(-acc[j]));
            sc[w][eq + j] = s;
            sfc[w][eq + j] = s + bias[eq + j];
        }
    }
    __syncthreads();

    if (lane == 0) {
        float gs[4];
        for (int gg = 0; gg < 4; ++gg) {
            float m1 = -1e30f, m2 = -1e30f;
            for (int j = 0; j < 8; ++j) {
                float v = sfc[w][gg * 8 + j];
                if (v > m1) { m2 = m1; m1 = v; }
                else if (v > m2) { m2 = v; }
            }
            gs[gg] = m1 + m2;
        }
        int g1 = 0;
        for (int gg = 1; gg < 4; ++gg) if (gs[gg] > gs[g1]) g1 = gg;
        int g2 = (g1 == 0) ? 1 : 0;
        for (int gg = 0; gg < 4; ++gg)
            if (gg != g1 && gs[gg] > gs[g2]) g2 = gg;

        unsigned allow = (0xFFu << (g1 * 8)) | (0xFFu << (g2 * 8));
        unsigned taken = 0u;
        int   isel[8];
        float wsel[8];
        float wsum = 0.f;
        for (int k = 0; k < 8; ++k) {
            int best = 0; float bv = -1e30f;
            for (int e2 = 0; e2 < 32; ++e2) {
                if (((allow >> e2) & 1u) && !((taken >> e2) & 1u)) {
                    float v = sfc[w][e2];
                    if (v > bv) { bv = v; best = e2; }
                }
            }
            taken |= 1u << best;
            isel[k] = best;
            wsel[k] = sc[w][best];
            wsum += sc[w][best];
        }
        const float f = 2.5f / wsum;
        for (int k = 0; k < 8; ++k) {
            tidx[t * 8 + k] = isel[k];
            tw[t * 8 + k] = wsel[k] * f;
        }
    }
}

// ---------------------------------------------------------------------------
// Build per-expert token lists (ascending token id); record each token's
// position within its expert's list (for the atomic-free combine).
// ---------------------------------------------------------------------------
__global__ __launch_bounds__(64) void build_k(
    const int* __restrict__ tidx, int* __restrict__ ltok,
    int* __restrict__ ppos, int* __restrict__ counts)
{
    const int e = blockIdx.x;
    const int lane = threadIdx.x;
    int cnt = 0;
    for (int t0 = 0; t0 < T_TOK; t0 += 64) {
        const int t = t0 + lane;
        int sel = 0, kk = 0;
        #pragma unroll
        for (int k = 0; k < 8; ++k) {
            if (tidx[t * 8 + k] == e) { sel = 1; kk = k; }
        }
        unsigned long long m = __ballot(sel);
        int pos = __popcll(m & ((1ull << lane) - 1ull));
        if (sel) {
            ltok[e * T_TOK + cnt + pos] = t;
            ppos[t * 8 + kk] = cnt + pos;
        }
        cnt += __popcll(m);
    }
    if (lane == 0) counts[e] = cnt;
}

__global__ void prefix_k(const int* __restrict__ counts, int* __restrict__ offsets)
{
    if (threadIdx.x == 0) {
        int off = 0;
        for (int e = 0; e < E_NUM; ++e) { offsets[e] = off; off += counts[e]; }
    }
}

// ---------------------------------------------------------------------------
// Combine: out[t] = shd[t] + sum_k tw[t,k] * yd[offsets[e_k] + ppos[t,k]].
// One 256-thread block per token; 8 cols per thread.
// ---------------------------------------------------------------------------
__global__ __launch_bounds__(256) void combine_k(
    const int* __restrict__ tidx, const float* __restrict__ tw,
    const int* __restrict__ offsets, const int* __restrict__ ppos,
    const unsigned short* __restrict__ shd, const unsigned short* __restrict__ yd,
    float* __restrict__ out)
{
    const int t = blockIdx.x;
    const int h = threadIdx.x * 8;
    u16x8 sv = *(const u16x8*)(shd + (size_t)t * H_DIM + h);
    float a[8];
    #pragma unroll
    for (int j = 0; j < 8; ++j) a[j] = bf2f(sv[j]);
    #pragma unroll
    for (int k = 0; k < 8; ++k) {
        int e = tidx[t * 8 + k];
        float w = tw[t * 8 + k];
        size_t row = (size_t)(offsets[e] + ppos[t * 8 + k]);
        u16x8 v = *(const u16x8*)(yd + row * H_DIM + h);
        #pragma unroll
        for (int j = 0; j < 8; ++j) a[j] += w * bf2f(v[j]);
    }
    f32x4 lo = { a[0], a[1], a[2], a[3] };
    f32x4 hi = { a[4], a[5], a[6], a[7] };
    *(f32x4*)(out + (size_t)t * H_DIM + h)     = lo;
    *(f32x4*)(out + (size_t)t * H_DIM + h + 4) = hi;
}

// ---------------------------------------------------------------------------
// GEMM: BM x 64 tile, BK=128, 512 threads (8 waves: 4M x 2N, wave WRx32).
// A (bf16 row-major) is REGISTER-DIRECT: the mfma A-fragment is 16B/lane
// contiguous, loaded straight from global (no LDS, no barrier involvement).
// Only B goes through LDS (fp32->bf16 transposed, swizzled, double-buffered,
// depth-2 register pipeline). ONE barrier per BK=128 (4 MFMA sub-steps).
// MSPLIT: y-grid doubled, second half = (B2g, out2).  Output always bf16.
// ---------------------------------------------------------------------------
template<int MSPLIT, int EXPERT, int GATHER, int BM>
__global__ __launch_bounds__(512) void gemm_k(
    const unsigned short* __restrict__ A,
    const float* __restrict__ B1g, const float* __restrict__ B2g,
    unsigned short* __restrict__ out1, unsigned short* __restrict__ out2,
    const int* __restrict__ counts, const int* __restrict__ offsets,
    const int* __restrict__ ltok,
    int M, int N, int K)
{
    constexpr int WR = BM / 4;         // rows per wave strip
    constexpr int FM = WR / 16;        // A frags per wave

    const int e = blockIdx.z;
    const int Mloc = EXPERT ? counts[e] : M;
    const int rb = EXPERT ? offsets[e] : 0;

    int ymat = 0, ypanel = blockIdx.y;
    if (MSPLIT) {
        const int half = gridDim.y >> 1;
        ymat = (blockIdx.y >= half) ? 1 : 0;
        ypanel -= ymat * half;
    }
    const float* B = ymat ? B2g : B1g;
    unsigned short* outp = ymat ? out2 : out1;
    if (EXPERT) B += (size_t)e * K * N;
    const int colB = ypanel * 64;

    __shared__ unsigned short lB[2][64 * 128];

    const int tid = threadIdx.x;
    const int lane = tid & 63;
    const int wv = tid >> 6;
    const int wm = wv >> 1;            // 0..3  M strip
    const int wn = wv & 1;             // 0..1  N half
    const int koff = (lane >> 4) * 8;

    // ---- B staging: thread -> 4k x 4n micro-tile (512 = 16nq x 32kq) ----
    const int nq = tid & 15;
    const int kq = tid >> 4;           // 0..31
    const float* bp = B + (size_t)(4 * kq) * N + colB + nq * 4;

    f32x4 acc[FM][2];
    f32x4 pbX[4], pbY[4];
    const unsigned short* ap[FM];

    auto stageLoad = [&](int k0, f32x4 (&pb)[4]) {
        #pragma unroll
        for (int j = 0; j < 4; ++j)
            pb[j] = *(const f32x4*)(bp + (size_t)(k0 + j) * N);
    };
    auto stageStore = [&](int p, f32x4 (&pb)[4]) {
        #pragma unroll
        for (int j2 = 0; j2 < 4; ++j2) {
            u16x4 h = { f2bf(pb[0][j2]), f2bf(pb[1][j2]),
                        f2bf(pb[2][j2]), f2bf(pb[3][j2]) };
            *(u16x4*)&lB[p][swzB(nq * 4 + j2, kq * 4)] = h;
        }
    };

    const int nk = K >> 7;             // K/128: 8 or 16

    for (int row0 = blockIdx.x * BM; row0 < Mloc; row0 += gridDim.x * BM) {
        // A fragment row pointers (register-direct)
        #pragma unroll
        for (int fm = 0; fm < FM; ++fm) {
            int rr = row0 + wm * WR + fm * 16 + (lane & 15);
            if (rr >= Mloc) rr = Mloc - 1;
            int grow = GATHER ? ltok[e * T_TOK + rr] : (rb + rr);
            ap[fm] = A + (size_t)grow * K + koff;
        }
        #pragma unroll
        for (int a = 0; a < FM; ++a)
            #pragma unroll
            for (int b = 0; b < 2; ++b)
                acc[a][b] = f32x4{0.f, 0.f, 0.f, 0.f};

        stageLoad(0, pbX);
        stageLoad(128, pbY);
        __syncthreads();               // prior m-tile readers done (rarely taken twice)
        stageStore(0, pbX);
        __syncthreads();

        for (int kt = 0; kt < nk; ++kt) {
            const int p = kt & 1;
            if (kt + 2 < nk) stageLoad((kt + 2) << 7, p ? pbY : pbX);
            const int kb = kt << 7;
            #pragma unroll
            for (int ks = 0; ks < 4; ++ks) {
                s16x8 af[FM], bf[2];
                #pragma unroll
                for (int fm = 0; fm < FM; ++fm)
                    af[fm] = *(const s16x8*)(ap[fm] + kb + ks * 32);
                #pragma unroll
                for (int fn = 0; fn < 2; ++fn)
                    bf[fn] = *(const s16x8*)&lB[p][swzB(wn * 32 + fn * 16 + (lane & 15),
                                                        ks * 32 + koff)];
                #pragma unroll
                for (int fm = 0; fm < FM; ++fm)
                    #pragma unroll
                    for (int fn = 0; fn < 2; ++fn)
                        acc[fm][fn] = __builtin_amdgcn_mfma_f32_16x16x32_bf16(
                            af[fm], bf[fn], acc[fm][fn], 0, 0, 0);
            }
            if (kt + 1 < nk) {
                stageStore(p ^ 1, p ? pbX : pbY);   // counted vmcnt: newer loads fly
                __syncthreads();
            }
        }

        // ---- epilogue: bf16 store ----
        const int fr = (lane >> 4) << 2;
        const int fc = lane & 15;
        #pragma unroll
        for (int fm = 0; fm < FM; ++fm)
            #pragma unroll
            for (int fn = 0; fn < 2; ++fn)
                #pragma unroll
                for (int j = 0; j < 4; ++j) {
                    int r = wm * WR + fm * 16 + fr + j;
                    if (row0 + r < Mloc) {
                        int cc = colB + wn * 32 + fn * 16 + fc;
                        outp[(size_t)(rb + row0 + r) * N + cc] = f2bf(acc[fm][fn][j]);
                    }
                }
    }
}

// ---------------------------------------------------------------------------
extern "C" void kernel_launch(void* const* d_in, const int* in_sizes, int n_in,
                              void* d_out, int out_size, void* d_ws, size_t ws_size,
                              hipStream_t stream) {
    const float* x       = (const float*)d_in[0];
    const float* gate_w  = (const float*)d_in[1];
    const float* bias    = (const float*)d_in[2];
    const float* w_gate  = (const float*)d_in[3];
    const float* w_up    = (const float*)d_in[4];
    const float* w_down  = (const float*)d_in[5];
    const float* sw_gate = (const float*)d_in[6];
    const float* sw_up   = (const float*)d_in[7];
    const float* sw_down = (const float*)d_in[8];
    float* out = (float*)d_out;

    char* ws = (char*)d_ws;
    int*   topk_idx = (int*)ws;                        // 32 KB
    float* topk_w   = (float*)(ws + 32768);            // 32 KB
    int*   counts   = (int*)(ws + 65536);              // 128 B
    int*   offsets  = (int*)(ws + 65664);              // 128 B
    int*   ppos     = (int*)(ws + 65792);              // 32 KB
    int*   ltok     = (int*)(ws + 98560);              // 128 KB
    unsigned short* xbf = (unsigned short*)(ws + 262144);            // 4 MB
    unsigned short* g_s = xbf + (size_t)T_TOK * H_DIM;               // 4 MB
    unsigned short* u_s = g_s + (size_t)T_TOK * IS_DIM;              // 4 MB
    unsigned short* shd = u_s + (size_t)T_TOK * IS_DIM;              // 4 MB
    unsigned short* g_r = shd + (size_t)T_TOK * H_DIM;               // 16 MB
    unsigned short* u_r = g_r + (size_t)T_TOK * 8 * I_DIM;           // 16 MB
    unsigned short* yd  = u_r + (size_t)T_TOK * 8 * I_DIM;           // 32 MB

    cvt_k<<<T_TOK * H_DIM / 2048, 256, 0, stream>>>(x, xbf);
    route_k<<<T_TOK / 4, 256, 0, stream>>>(x, gate_w, bias, topk_idx, topk_w);
    build_k<<<E_NUM, 64, 0, stream>>>(topk_idx, ltok, ppos, counts);
    prefix_k<<<1, 64, 0, stream>>>(counts, offsets);

    // shared gate/up (y-split): y 0..31 -> gate, 32..63 -> up; BM=256
    gemm_k<1,0,0,256><<<dim3(4, 64, 1), 512, 0, stream>>>(
        xbf, sw_gate, sw_up, g_s, u_s, nullptr, nullptr, nullptr,
        T_TOK, IS_DIM, H_DIM);
    silu_k<<<T_TOK * IS_DIM / 2048, 256, 0, stream>>>(g_s, u_s, g_s);

    // routed gate/up (y-split): BM=320 covers counts in one tile; weights once
    gemm_k<1,1,1,320><<<dim3(1, 32, E_NUM), 512, 0, stream>>>(
        xbf, w_gate, w_up, g_r, u_r, counts, offsets, ltok,
        T_TOK, I_DIM, H_DIM);
    silu_k<<<T_TOK * 8 * I_DIM / 2048, 256, 0, stream>>>(g_r, u_r, g_r);

    // shared down -> shd (bf16)
    gemm_k<0,0,0,256><<<dim3(4, 32, 1), 512, 0, stream>>>(
        g_s, sw_down, nullptr, shd, nullptr, nullptr, nullptr, nullptr,
        T_TOK, H_DIM, IS_DIM);

    // routed down -> yd rows (bf16, no atomics)
    gemm_k<0,1,0,320><<<dim3(1, 32, E_NUM), 512, 0, stream>>>(
        g_r, w_down, nullptr, yd, nullptr, counts, offsets, ltok,
        T_TOK, H_DIM, I_DIM);

    // out[t] = shd[t] + sum_k w_k * yd[row_k]
    combine_k<<<T_TOK, 256, 0, stream>>>(
        topk_idx, topk_w, offsets, ppos, shd, yd, out);
}